// Round 3
// baseline (453.353 us; speedup 1.0000x reference)
//
#include <hip/hip_runtime.h>
#include <hip/hip_bf16.h>
#include <math.h>

#define D_MODEL 512
#define HEADS   8
#define D_K     64
#define T_SEQ   2048
#define B_SZ    4
#define NROWS   (B_SZ * T_SEQ)   // 8192

typedef __attribute__((ext_vector_type(8))) short short8;
typedef __attribute__((ext_vector_type(4))) float f32x4;

__device__ __forceinline__ ushort f2bf(float f) {
    union { float f; unsigned u; } v; v.f = f;
    unsigned u = v.u;
    unsigned r = (u + 0x7FFFu + ((u >> 16) & 1u)) >> 16;
    return (ushort)r;
}

// ---------------------------------------------------------------- embed + PE
__global__ __launch_bounds__(128) void k_embed(
    const int* __restrict__ tokens, const float* __restrict__ emb,
    float* __restrict__ xf, ushort* __restrict__ xb,
    float* __restrict__ mask_out)
{
    int row = blockIdx.x;              // 0..NROWS-1
    int t   = row & (T_SEQ - 1);
    int tok = tokens[row];
    if (threadIdx.x == 0)
        mask_out[row] = (tok == 0) ? 1.0f : 0.0f;
    const float* e = emb + (size_t)tok * D_MODEL;
#pragma unroll
    for (int i = 0; i < 4; ++i) {
        int d = threadIdx.x + 128 * i;
        float freq = powf(10000.0f, -(float)(d & ~1) / 512.0f);
        float ang  = (float)t * freq;
        float pe   = (d & 1) ? cosf(ang) : sinf(ang);
        float x    = e[d] * 22.627416997969522f + pe;
        xf[(size_t)row * D_MODEL + d] = x;
        xb[(size_t)row * D_MODEL + d] = f2bf(x);
    }
}

// ---------------------------------------------------------------- casts
__global__ void k_cast_bf16(const float* __restrict__ src, ushort* __restrict__ dst,
                            int n, float scale) {
    int i = blockIdx.x * 256 + threadIdx.x;
    if (i < n) dst[i] = f2bf(src[i] * scale);
}
__global__ void k_scale_f32(const float* __restrict__ src, float* __restrict__ dst,
                            int n, float scale) {
    int i = blockIdx.x * 256 + threadIdx.x;
    if (i < n) dst[i] = src[i] * scale;
}

// ---------------------------------------------------------------- GEMM (bf16 MFMA)
// C[M,N] = A[M,K] @ B[K,N] + bias ; A,B bf16 row-major, acc f32.
// block = 256 threads = 4 waves (2x2), block tile 64x64, wave tile 32x32.
template<bool OUT_BF16, bool RELU>
__global__ __launch_bounds__(256) void k_gemm(
    const ushort* __restrict__ A, const ushort* __restrict__ Bw,
    const float* __restrict__ bias, void* __restrict__ Cout,
    int M, int N, int K)
{
    int w  = threadIdx.x >> 6;
    int l  = threadIdx.x & 63;
    int lr = l & 15, lg = l >> 4;
    int row0 = blockIdx.y * 64 + (w >> 1) * 32;
    int col0 = blockIdx.x * 64 + (w & 1) * 32;

    f32x4 acc[2][2] = {};
    for (int k0 = 0; k0 < K; k0 += 32) {
        short8 a[2], b[2];
#pragma unroll
        for (int m = 0; m < 2; ++m)
            a[m] = *(const short8*)(A + (size_t)(row0 + m * 16 + lr) * K + k0 + 8 * lg);
#pragma unroll
        for (int n = 0; n < 2; ++n) {
            const ushort* bp = Bw + (size_t)(k0 + 8 * lg) * N + col0 + n * 16 + lr;
            short8 tv;
#pragma unroll
            for (int i = 0; i < 8; ++i) tv[i] = (short)bp[(size_t)i * N];
            b[n] = tv;
        }
#pragma unroll
        for (int m = 0; m < 2; ++m)
#pragma unroll
            for (int n = 0; n < 2; ++n)
                acc[m][n] = __builtin_amdgcn_mfma_f32_16x16x32_bf16(a[m], b[n], acc[m][n], 0, 0, 0);
    }
#pragma unroll
    for (int m = 0; m < 2; ++m)
#pragma unroll
        for (int n = 0; n < 2; ++n) {
            int col = col0 + n * 16 + lr;
            float bs = bias ? bias[col] : 0.0f;
#pragma unroll
            for (int j = 0; j < 4; ++j) {
                int rowg = row0 + m * 16 + 4 * lg + j;
                float v = acc[m][n][j] + bs;
                if (RELU) v = fmaxf(v, 0.0f);
                if (OUT_BF16) ((ushort*)Cout)[(size_t)rowg * N + col] = f2bf(v);
                else          ((float*) Cout)[(size_t)rowg * N + col] = v;
            }
        }
}

// ---------------------------------------------------------------- flash attention
// grid: B*H*(T/64) blocks, 4 waves; each wave: 16 q rows, full online softmax.
// Q pre-scaled by 1/sqrt(D_K).
__global__ __launch_bounds__(256) void k_attn(
    const ushort* __restrict__ Q, const ushort* __restrict__ Kb,
    const ushort* __restrict__ V, const int* __restrict__ tokens,
    ushort* __restrict__ Out)
{
    __shared__ ushort plds[4][16 * 32];
    int w  = threadIdx.x >> 6;
    int l  = threadIdx.x & 63;
    int lr = l & 15, lg = l >> 4;

    int qt = blockIdx.x & 31;          // T/64 = 32
    int h  = (blockIdx.x >> 5) & 7;
    int b  = blockIdx.x >> 8;
    int q0 = qt * 64 + w * 16;

    const ushort* Qh = Q + (size_t)b * T_SEQ * D_MODEL + h * D_K;
    short8 aq[2];
#pragma unroll
    for (int kh = 0; kh < 2; ++kh)
        aq[kh] = *(const short8*)(Qh + (size_t)(q0 + lr) * D_MODEL + kh * 32 + 8 * lg);

    float m_run[4], l_run[4];
#pragma unroll
    for (int j = 0; j < 4; ++j) { m_run[j] = -1e30f; l_run[j] = 0.0f; }
    f32x4 acc[4] = {};

    const int* tk = tokens + b * T_SEQ;

    for (int kt = 0; kt < T_SEQ / 32; ++kt) {
        f32x4 s[2];
#pragma unroll
        for (int sub = 0; sub < 2; ++sub) {
            int ks = kt * 32 + sub * 16;
            f32x4 sf = {};
#pragma unroll
            for (int kh = 0; kh < 2; ++kh) {
                short8 bk = *(const short8*)(Kb + (size_t)(b * T_SEQ + ks + lr) * D_MODEL
                                             + h * D_K + kh * 32 + 8 * lg);
                sf = __builtin_amdgcn_mfma_f32_16x16x32_bf16(aq[kh], bk, sf, 0, 0, 0);
            }
            bool pad = (tk[ks + lr] == 0);
            if (pad) {
#pragma unroll
                for (int j = 0; j < 4; ++j) sf[j] = -1e30f;
            }
            s[sub] = sf;
        }

        float pv[2][4];
#pragma unroll
        for (int j = 0; j < 4; ++j) {
            float mx = fmaxf(s[0][j], s[1][j]);
#pragma unroll
            for (int d = 1; d < 16; d <<= 1) mx = fmaxf(mx, __shfl_xor(mx, d, 16));
            float mnew = fmaxf(m_run[j], mx);
            float sc = __expf(m_run[j] - mnew);
            float p0 = __expf(s[0][j] - mnew);
            float p1 = __expf(s[1][j] - mnew);
            float ts = p0 + p1;
#pragma unroll
            for (int d = 1; d < 16; d <<= 1) ts += __shfl_xor(ts, d, 16);
            l_run[j] = l_run[j] * sc + ts;
            m_run[j] = mnew;
#pragma unroll
            for (int c = 0; c < 4; ++c) acc[c][j] *= sc;
            pv[0][j] = p0; pv[1][j] = p1;
        }

        ushort* P = plds[w];
#pragma unroll
        for (int sub = 0; sub < 2; ++sub)
#pragma unroll
            for (int j = 0; j < 4; ++j)
                P[(4 * lg + j) * 32 + sub * 16 + lr] = f2bf(pv[sub][j]);
        // wave-local LDS roundtrip; compiler inserts lgkmcnt waits
        short8 ap = *(const short8*)(P + lr * 32 + 8 * lg);
#pragma unroll
        for (int c = 0; c < 4; ++c) {
            const ushort* vp = V + (size_t)(b * T_SEQ + kt * 32 + 8 * lg) * D_MODEL
                               + h * D_K + c * 16 + lr;
            short8 bv;
#pragma unroll
            for (int i = 0; i < 8; ++i) bv[i] = (short)vp[(size_t)i * D_MODEL];
            acc[c] = __builtin_amdgcn_mfma_f32_16x16x32_bf16(ap, bv, acc[c], 0, 0, 0);
        }
    }

#pragma unroll
    for (int c = 0; c < 4; ++c)
#pragma unroll
        for (int j = 0; j < 4; ++j) {
            float o = acc[c][j] / l_run[j];
            Out[(size_t)(b * T_SEQ + q0 + 4 * lg + j) * D_MODEL + h * D_K + c * 16 + lr] = f2bf(o);
        }
}

// ---------------------------------------------------------------- add + layernorm
// 1 wave per row of 512; block = 256 threads = 4 rows.
// Always writes f32 to `of`; if WRITE_B also writes bf16 to `ob`.
template<bool WRITE_B>
__global__ __launch_bounds__(256) void k_ln(
    const float* __restrict__ A, const float* __restrict__ Bres,
    const float* __restrict__ g, const float* __restrict__ bb,
    float* __restrict__ of, ushort* __restrict__ ob)
{
    int row = blockIdx.x * 4 + (threadIdx.x >> 6);
    int l = threadIdx.x & 63;
    const float* pa = A + (size_t)row * D_MODEL;
    const float* pb = Bres + (size_t)row * D_MODEL;
    float v[8];
    float s = 0.0f, ss = 0.0f;
#pragma unroll
    for (int i = 0; i < 2; ++i) {
        f32x4 va = *(const f32x4*)(pa + i * 256 + l * 4);
        f32x4 vb = *(const f32x4*)(pb + i * 256 + l * 4);
#pragma unroll
        for (int j = 0; j < 4; ++j) {
            float x = va[j] + vb[j];
            v[i * 4 + j] = x; s += x; ss += x * x;
        }
    }
#pragma unroll
    for (int d = 1; d < 64; d <<= 1) { s += __shfl_xor(s, d); ss += __shfl_xor(ss, d); }
    float mu  = s * (1.0f / 512.0f);
    float var = ss * (1.0f / 512.0f) - mu * mu;
    float rs  = rsqrtf(var + 1e-5f);
#pragma unroll
    for (int i = 0; i < 2; ++i)
#pragma unroll
        for (int j = 0; j < 4; ++j) {
            int d = i * 256 + l * 4 + j;
            float o = (v[i * 4 + j] - mu) * rs * g[d] + bb[d];
            of[(size_t)row * D_MODEL + d] = o;
            if (WRITE_B) ob[(size_t)row * D_MODEL + d] = f2bf(o);
        }
}

// ---------------------------------------------------------------- launcher
extern "C" void kernel_launch(void* const* d_in, const int* in_sizes, int n_in,
                              void* d_out, int out_size, void* d_ws, size_t ws_size,
                              hipStream_t stream)
{
    const int*   tokens = (const int*)  d_in[0];
    const float* emb    = (const float*)d_in[1];
    const float* wq     = (const float*)d_in[2];
    const float* bq     = (const float*)d_in[3];
    const float* wk     = (const float*)d_in[4];
    const float* bk     = (const float*)d_in[5];
    const float* wv     = (const float*)d_in[6];
    const float* bv     = (const float*)d_in[7];
    const float* wo     = (const float*)d_in[8];
    const float* bo     = (const float*)d_in[9];
    const float* w1     = (const float*)d_in[10];
    const float* b1     = (const float*)d_in[11];
    const float* w2     = (const float*)d_in[12];
    const float* b2     = (const float*)d_in[13];
    const float* ln1_g  = (const float*)d_in[14];
    const float* ln1_b  = (const float*)d_in[15];
    const float* ln2_g  = (const float*)d_in[16];
    const float* ln2_b  = (const float*)d_in[17];

    char* ws = (char*)d_ws;
    // workspace layout (bytes)
    float*  xf   = (float*)(ws + 0);               // 16,777,216
    ushort* xb   = (ushort*)(ws + 16777216);       //  8,388,608  (later: attn out)
    ushort* Qb   = (ushort*)(ws + 25165824);       //  8,388,608  (later: h bf16)
    ushort* Kbuf = (ushort*)(ws + 33554432);       //  8,388,608  \ later: ff1 (16 MB)
    ushort* Vbuf = (ushort*)(ws + 41943040);       //  8,388,608  /
    float*  AVf  = (float*)(ws + 50331648);        // 16,777,216  (later: ff2)
    float*  hf   = (float*)(ws + 67108864);        // 16,777,216
    ushort* wqb  = (ushort*)(ws + 83886080);       // 524,288 each
    ushort* wkb  = wqb + 262144;
    ushort* wvb  = wkb + 262144;
    ushort* wob  = wvb + 262144;
    ushort* w1b  = wob + 262144;                   // 1,048,576
    ushort* w2b  = w1b + 524288;                   // 1,048,576
    float*  bqs  = (float*)(w2b + 524288);         // 2 KB

    ushort* atb  = xb;     // attention output (bf16), reuses x_bf16
    ushort* hb   = Qb;     // h bf16, reuses Q
    ushort* ff1b = Kbuf;   // ff1 bf16 (8192x1024), reuses K+V
    float*  ff2f = AVf;    // ff2 f32, reuses AV

    float* out_f    = (float*)d_out;                       // f32 output!
    float* mask_out = out_f + (size_t)NROWS * D_MODEL;     // f32 0/1 mask

    // 1. embedding + positional encoding (+ mask output)
    k_embed<<<NROWS, 128, 0, stream>>>(tokens, emb, xf, xb, mask_out);

    // 2. weight casts (fold 1/sqrt(d_k)=0.125 into wq/bq)
    k_cast_bf16<<<1024, 256, 0, stream>>>(wq, wqb, 262144, 0.125f);
    k_cast_bf16<<<1024, 256, 0, stream>>>(wk, wkb, 262144, 1.0f);
    k_cast_bf16<<<1024, 256, 0, stream>>>(wv, wvb, 262144, 1.0f);
    k_cast_bf16<<<1024, 256, 0, stream>>>(wo, wob, 262144, 1.0f);
    k_cast_bf16<<<2048, 256, 0, stream>>>(w1, w1b, 524288, 1.0f);
    k_cast_bf16<<<2048, 256, 0, stream>>>(w2, w2b, 524288, 1.0f);
    k_scale_f32<<<2, 256, 0, stream>>>(bq, bqs, 512, 0.125f);

    // 3. QKV projections
    k_gemm<true,  false><<<dim3(8, 128), 256, 0, stream>>>(xb, wqb, bqs, Qb,   NROWS, 512, 512);
    k_gemm<true,  false><<<dim3(8, 128), 256, 0, stream>>>(xb, wkb, bk,  Kbuf, NROWS, 512, 512);
    k_gemm<true,  false><<<dim3(8, 128), 256, 0, stream>>>(xb, wvb, bv,  Vbuf, NROWS, 512, 512);

    // 4. attention
    k_attn<<<B_SZ * HEADS * (T_SEQ / 64), 256, 0, stream>>>(Qb, Kbuf, Vbuf, tokens, atb);

    // 5. output projection
    k_gemm<false, false><<<dim3(8, 128), 256, 0, stream>>>(atb, wob, bo, AVf, NROWS, 512, 512);

    // 6. LN1: h = LN(av + x)
    k_ln<true><<<NROWS / 4, 256, 0, stream>>>(AVf, xf, ln1_g, ln1_b, hf, hb);

    // 7. FFN
    k_gemm<true,  true ><<<dim3(16, 128), 256, 0, stream>>>(hb,   w1b, b1, ff1b, NROWS, 1024, 512);
    k_gemm<false, false><<<dim3(8, 128), 256, 0, stream>>>(ff1b, w2b, b2, ff2f, NROWS, 512, 1024);

    // 8. LN2: out = LN(h + ff)  (f32 to d_out)
    k_ln<false><<<NROWS / 4, 256, 0, stream>>>(ff2f, hf, ln2_g, ln2_b, out_f, nullptr);
}